// Round 4
// baseline (136.301 us; speedup 1.0000x reference)
//
#include <hip/hip_runtime.h>

typedef __attribute__((ext_vector_type(8))) short short8;
typedef __attribute__((ext_vector_type(8))) unsigned short u16x8;
typedef __attribute__((ext_vector_type(4))) unsigned short u16x4;
typedef __attribute__((ext_vector_type(4))) float f32x4;

#define L2E 1.44269504f

__device__ __forceinline__ unsigned short f2bf(float f){
  unsigned u = __float_as_uint(f);
  u += 0x7fffu + ((u >> 16) & 1u);
  return (unsigned short)(u >> 16);
}
__device__ __forceinline__ float bf2f(unsigned short h){
  return __uint_as_float(((unsigned)h) << 16);
}

// ---------------- prep: fold score_w through q_w / kv_w ----------------
__global__ void prep_vecs(const float* __restrict__ qw, const float* __restrict__ qb,
                          const float* __restrict__ kvw, const float* __restrict__ kvb,
                          const float* __restrict__ scw, const float* __restrict__ scb,
                          float* __restrict__ qv, float* __restrict__ kvv,
                          float* __restrict__ cqck){
  int d = threadIdx.x; // 0..127
  const float4* qr = (const float4*)(qw + d*128);
  const float4* kr = (const float4*)(kvw + d*256);
  float a = 0.f, c = 0.f;
  #pragma unroll 8
  for (int i = 0; i < 32; ++i){
    float4 q4 = qr[i];
    float4 w4 = *(const float4*)(scw + i*4);
    a = fmaf(q4.x, w4.x, a); a = fmaf(q4.y, w4.y, a);
    a = fmaf(q4.z, w4.z, a); a = fmaf(q4.w, w4.w, a);
    float4 k4 = kr[i];
    float4 v4 = *(const float4*)(scw + 128 + i*4);
    c = fmaf(k4.x, v4.x, c); c = fmaf(k4.y, v4.y, c);
    c = fmaf(k4.z, v4.z, c); c = fmaf(k4.w, v4.w, c);
  }
  qv[d] = a; kvv[d] = c;
  if (d == 0){
    float cq = scb[0], ck = 0.f;
    #pragma unroll 8
    for (int i = 0; i < 32; ++i){
      float4 qb4 = *(const float4*)(qb + i*4);
      float4 w4  = *(const float4*)(scw + i*4);
      float4 kb4 = *(const float4*)(kvb + i*4);
      float4 v4  = *(const float4*)(scw + 128 + i*4);
      cq = fmaf(qb4.x, w4.x, cq); cq = fmaf(qb4.y, w4.y, cq);
      cq = fmaf(qb4.z, w4.z, cq); cq = fmaf(qb4.w, w4.w, cq);
      ck = fmaf(kb4.x, v4.x, ck); ck = fmaf(kb4.y, v4.y, ck);
      ck = fmaf(kb4.z, v4.z, ck); ck = fmaf(kb4.w, v4.w, ck);
    }
    cqck[0] = cq; cqck[1] = ck;
  }
}

// W2T[ho][din] = sum_h kv_w[din][128+h] * out_w[h][ho]   (bf16, transposed)
__global__ __launch_bounds__(256) void prep_w2(const float* __restrict__ kvw,
                          const float* __restrict__ kvb,
                          const float* __restrict__ outw, const float* __restrict__ outb,
                          unsigned short* __restrict__ w2t, float* __restrict__ c2){
  int blk = blockIdx.x;
  if (blk < 64){
    int idx = blk*256 + threadIdx.x;
    int di = idx >> 7, ho = idx & 127;
    const float* kr = kvw + di*256 + 128;
    float s = 0.f;
    for (int h = 0; h < 128; ++h) s = fmaf(kr[h], outw[h*128 + ho], s);
    w2t[ho*128 + di] = f2bf(s);
  } else if (threadIdx.x < 128){
    int ho = threadIdx.x;
    float s = outb[ho];
    for (int h = 0; h < 128; ++h) s = fmaf(kvb[128 + h], outw[h*128 + ho], s);
    c2[ho] = s;
  }
}

// sq'[b*1024+m] = L2E * (mf[b,m,:].qv + cq)
__global__ __launch_bounds__(256) void prep_sq(const float* __restrict__ mf,
                          const float* __restrict__ qv, const float* __restrict__ cqck,
                          float* __restrict__ sqp){
  int row = blockIdx.x*4 + (threadIdx.x >> 6);
  int lane = threadIdx.x & 63;
  float s = mf[row*128 + lane] * qv[lane] + mf[row*128 + 64 + lane] * qv[64 + lane];
  #pragma unroll
  for (int o = 32; o; o >>= 1) s += __shfl_xor(s, o, 64);
  if (lane == 0) sqp[row] = L2E * (s + cqck[0]);
}

// sk'[b*4096+c] = L2E * (of[b,c,:].kvv + ck) ; ofT[b][d][c] = bf16(of[b][c][d])
__global__ __launch_bounds__(256) void prep_sk_tr(const float* __restrict__ of,
                          const float* __restrict__ kvv, const float* __restrict__ cqck,
                          float* __restrict__ skp, unsigned short* __restrict__ ofT){
  __shared__ unsigned short tile[64*130];
  int b  = blockIdx.x >> 6;
  int c0 = (blockIdx.x & 63) << 6;
  int t  = threadIdx.x;
  int r  = t >> 2, dq = (t & 3) << 5;
  const float* src = of + ((size_t)(b*4096 + c0 + r))*128 + dq;
  float part = 0.f;
  #pragma unroll
  for (int j = 0; j < 32; j += 4){
    float4 v = *(const float4*)(src + j);
    part = fmaf(v.x, kvv[dq + j],     part);
    part = fmaf(v.y, kvv[dq + j + 1], part);
    part = fmaf(v.z, kvv[dq + j + 2], part);
    part = fmaf(v.w, kvv[dq + j + 3], part);
    tile[r*130 + dq + j]     = f2bf(v.x);
    tile[r*130 + dq + j + 1] = f2bf(v.y);
    tile[r*130 + dq + j + 2] = f2bf(v.z);
    tile[r*130 + dq + j + 3] = f2bf(v.w);
  }
  part += __shfl_xor(part, 1, 64);
  part += __shfl_xor(part, 2, 64);
  if ((t & 3) == 0) skp[b*4096 + c0 + r] = L2E * (part + cqck[1]);
  __syncthreads();
  int d = t >> 1, chh = (t & 1) << 5;
  unsigned short* dst = ofT + ((size_t)(b*128 + d))*4096 + c0 + chh;
  #pragma unroll
  for (int j = 0; j < 32; j += 8){
    u16x8 v;
    #pragma unroll
    for (int k = 0; k < 8; ++k) v[k] = tile[(chh + j + k)*130 + d];
    *(u16x8*)(dst + j) = v;
  }
}

// ---------------- main kernel: LDS-free, barrier-free ----------------
// Each WAVE independently owns one unit = (bmt = b*64+mt16, cs): 16 m-rows ×
// all 128 d, c-range [cs*(4096>>CSL2), +4096>>CSL2) in chunks of 128.
// Lane l -> m-row (l&15), k-slice (l>>4)*8: P is computed by exp2 directly
// into the MFMA A-fragment register order. B = ofT (L2-resident).
// Partial acc written as [unit][col][row] (f32x4 per (nt) store).
template<int CSL2>
__global__ __launch_bounds__(256, 2) void attn_main(
    const float* __restrict__ mask, const float* __restrict__ sqp,
    const float* __restrict__ skp, const unsigned short* __restrict__ ofT,
    float* __restrict__ pacc, float* __restrict__ prs)
{
  constexpr int CS  = 1 << CSL2;
  constexpr int NCH = 32 >> CSL2;           // chunks of 128 c
  const int t = threadIdx.x, w = t >> 6, l = t & 63;
  const int l15 = l & 15, l4 = l >> 4;
  const int unit = blockIdx.x*4 + w;
  const int cs   = unit & (CS - 1);
  const int bmt  = unit >> CSL2;            // b*64 + mt
  const int b    = bmt >> 6;
  const int m0   = (bmt & 63) << 4;
  const int c0   = cs << (12 - CSL2);

  const int grow = b*1024 + m0 + l15;
  const float sqv = sqp[grow];
  const float* mrow  = mask + (size_t)grow*4096 + c0 + l4*8;
  const float* skrow = skp + b*4096 + c0 + l4*8;
  const unsigned short* brow = ofT + ((size_t)(b*128 + l15))*4096 + c0 + l4*8;

  f32x4 acc[8];
  #pragma unroll
  for (int nt = 0; nt < 8; ++nt) acc[nt] = {0.f,0.f,0.f,0.f};
  float rsum = 0.f;

  float4 cm[8];                              // current chunk mask: [ks*2+h]
  #pragma unroll
  for (int q = 0; q < 8; ++q)
    cm[q] = *(const float4*)(mrow + (q>>1)*32 + (q&1)*4);

  for (int ch = 0; ch < NCH; ++ch){
    float4 nm[8];
    if (ch + 1 < NCH){
      #pragma unroll
      for (int q = 0; q < 8; ++q)
        nm[q] = *(const float4*)(mrow + (ch+1)*128 + (q>>1)*32 + (q&1)*4);
    }
    #pragma unroll
    for (int ks = 0; ks < 4; ++ks){
      float4 s0 = *(const float4*)(skrow + ch*128 + ks*32);
      float4 s1 = *(const float4*)(skrow + ch*128 + ks*32 + 4);
      const float sv[8] = {s0.x,s0.y,s0.z,s0.w,s1.x,s1.y,s1.z,s1.w};
      const float mv[8] = {cm[ks*2].x,cm[ks*2].y,cm[ks*2].z,cm[ks*2].w,
                           cm[ks*2+1].x,cm[ks*2+1].y,cm[ks*2+1].z,cm[ks*2+1].w};
      short8 pa;
      #pragma unroll
      for (int j = 0; j < 8; ++j){
        float s = sqv + sv[j];               // log2-domain (pre-scaled by L2E)
        s = fmaxf(s, 0.01f*s);               // leaky (positively homogeneous)
        s *= mv[j];                          // mask: 0 -> exp2(0)=1
        float p = __builtin_amdgcn_exp2f(s);
        unsigned short h = f2bf(p);
        pa[j] = (short)h;
        rsum += bf2f(h);                     // denominator matches bf16 numerator
      }
      #pragma unroll
      for (int nt = 0; nt < 8; ++nt){
        short8 bf = *(const short8*)(brow + (size_t)nt*65536 + ch*128 + ks*32);
        acc[nt] = __builtin_amdgcn_mfma_f32_16x16x32_bf16(pa, bf, acc[nt], 0, 0, 0);
      }
    }
    if (ch + 1 < NCH){
      #pragma unroll
      for (int q = 0; q < 8; ++q) cm[q] = nm[q];
    }
  }
  // row partial sums: lanes {l15, l15+16, l15+32, l15+48} share row l15
  rsum += __shfl_xor(rsum, 16, 64);
  rsum += __shfl_xor(rsum, 32, 64);
  if (l < 16) prs[unit*16 + l15] = rsum;

  // acc -> pacc[unit][col][row]: f32x4 covers rows l4*4..+3 of col nt*16+l15
  float* po = pacc + (size_t)unit*2048 + l15*16 + l4*4;
  #pragma unroll
  for (int nt = 0; nt < 8; ++nt)
    *(f32x4*)(po + nt*256) = acc[nt];
}

// ---------------- reduce partials + normalize + GEMM2 ----------------
// grid 128: blk = b*16 + mt64 (64-row tile) = 4 units (q) x CS cs-slices.
__global__ __launch_bounds__(256) void reduce_gemm2(
    const float* __restrict__ pacc, const float* __restrict__ prs,
    const unsigned short* __restrict__ w2t, const float* __restrict__ c2,
    float* __restrict__ out, int csl2)
{
  __shared__ unsigned short A2[64*128];   // 16 KB, row stride 256 B, swizzled
  __shared__ float rs[64];                // inverse rowsums
  const int bmt64 = blockIdx.x;
  const int b = bmt64 >> 4, mt = bmt64 & 15;
  const int CS = 1 << csl2;
  const int t = threadIdx.x;

  f32x4 a[8];
  #pragma unroll
  for (int i = 0; i < 8; ++i) a[i] = {0.f,0.f,0.f,0.f};
  for (int cs = 0; cs < CS; ++cs){
    #pragma unroll
    for (int i = 0; i < 8; ++i){
      const int flat = (i*256 + t)*4;          // over 4 units x 2048
      const int q = flat >> 11, f2 = flat & 2047;
      const float* pb = pacc + ((size_t)((bmt64*4 + q)*CS + cs))*2048 + f2;
      f32x4 v = *(const f32x4*)pb;
      a[i][0]+=v[0]; a[i][1]+=v[1]; a[i][2]+=v[2]; a[i][3]+=v[3];
    }
  }
  if (t < 64){
    float s = 0.f;
    const int q = t >> 4, r16 = t & 15;
    for (int cs = 0; cs < CS; ++cs) s += prs[((bmt64*4 + q)*CS + cs)*16 + r16];
    rs[t] = 1.f / s;
  }
  __syncthreads();
  #pragma unroll
  for (int i = 0; i < 8; ++i){
    const int flat = (i*256 + t)*4;
    const int q = flat >> 11, f2 = flat & 2047;
    const int col = f2 >> 4, r16 = f2 & 15;    // f2 = col*16 + row16 (+k)
    #pragma unroll
    for (int k = 0; k < 4; ++k){
      const int row = q*16 + r16 + k;
      unsigned short h = f2bf(a[i][k] * rs[row]);
      *(unsigned short*)((char*)A2 + row*256 + ((col*2) ^ ((row & 7) << 4))) = h;
    }
  }
  __syncthreads();

  const int w = t >> 6, l = t & 63, l15 = l & 15, l4 = l >> 4;
  f32x4 o[4][2];
  #pragma unroll
  for (int mf = 0; mf < 4; ++mf){ o[mf][0] = {0.f,0.f,0.f,0.f}; o[mf][1] = {0.f,0.f,0.f,0.f}; }
  const unsigned short* wp0 = w2t + (size_t)(w*32 + l15)*128 + l4*8;
  const char* ab = (const char*)A2 + l15*256;
  const int xa = (l15 & 7) << 4;
  #pragma unroll
  for (int ks = 0; ks < 4; ++ks){
    short8 b0 = *(const short8*)(wp0 + ks*32);
    short8 b1 = *(const short8*)(wp0 + 16*128 + ks*32);
    #pragma unroll
    for (int mf = 0; mf < 4; ++mf){
      short8 af = *(const short8*)(ab + mf*4096 + ((ks*64 + l4*16) ^ xa));
      o[mf][0] = __builtin_amdgcn_mfma_f32_16x16x32_bf16(af, b0, o[mf][0], 0, 0, 0);
      o[mf][1] = __builtin_amdgcn_mfma_f32_16x16x32_bf16(af, b1, o[mf][1], 0, 0, 0);
    }
  }
  #pragma unroll
  for (int mf = 0; mf < 4; ++mf)
    #pragma unroll
    for (int n = 0; n < 2; ++n){
      const int col = w*32 + n*16 + l15;
      const float cc = c2[col];
      #pragma unroll
      for (int j = 0; j < 4; ++j){
        const int row = mf*16 + l4*4 + j;
        out[((size_t)(b*1024 + mt*64 + row))*128 + col] = o[mf][n][j] + cc;
      }
    }
}

extern "C" void kernel_launch(void* const* d_in, const int* in_sizes, int n_in,
                              void* d_out, int out_size, void* d_ws, size_t ws_size,
                              hipStream_t stream){
  const float* of   = (const float*)d_in[0];
  const float* mf   = (const float*)d_in[1];
  const float* mask = (const float*)d_in[2];
  const float* qw   = (const float*)d_in[3];
  const float* qb   = (const float*)d_in[4];
  const float* kvw  = (const float*)d_in[5];
  const float* kvb  = (const float*)d_in[6];
  const float* scw  = (const float*)d_in[7];
  const float* scb  = (const float*)d_in[8];
  const float* outw = (const float*)d_in[9];
  const float* outb = (const float*)d_in[10];
  float* out = (float*)d_out;

  char* ws = (char*)d_ws;
  unsigned short* ofT  = (unsigned short*)(ws);             // 8 MiB
  unsigned short* w2t  = (unsigned short*)(ws + 8388608);   // 32 KiB
  float* c2   = (float*)(ws + 8421376);
  float* sqp  = (float*)(ws + 8421888);
  float* skp  = (float*)(ws + 8454656);
  float* qv   = (float*)(ws + 8585728);
  float* kvv  = (float*)(ws + 8586240);
  float* cqck = (float*)(ws + 8586752);
  const size_t fixed_end = 8587008;

  // pick largest C-split that fits: units = 512 << csl2 (one wave each)
  int csl2 = 3;
  while (csl2 > 1){
    size_t nunit = (size_t)512 << csl2;
    if (fixed_end + nunit*16*4 + nunit*2048*4 <= ws_size) break;
    --csl2;
  }
  size_t nunit = (size_t)512 << csl2;
  float* prs  = (float*)(ws + fixed_end);
  float* pacc = (float*)(ws + fixed_end + nunit*16*4);
  int nblk = (int)(nunit >> 2);

  prep_vecs<<<1, 128, 0, stream>>>(qw, qb, kvw, kvb, scw, scb, qv, kvv, cqck);
  prep_w2<<<65, 256, 0, stream>>>(kvw, kvb, outw, outb, w2t, c2);
  prep_sq<<<2048, 256, 0, stream>>>(mf, qv, cqck, sqp);
  prep_sk_tr<<<512, 256, 0, stream>>>(of, kvv, cqck, skp, ofT);
  switch (csl2){
    case 3: attn_main<3><<<nblk, 256, 0, stream>>>(mask, sqp, skp, ofT, pacc, prs); break;
    case 2: attn_main<2><<<nblk, 256, 0, stream>>>(mask, sqp, skp, ofT, pacc, prs); break;
    default: attn_main<1><<<nblk, 256, 0, stream>>>(mask, sqp, skp, ofT, pacc, prs); break;
  }
  reduce_gemm2<<<128, 256, 0, stream>>>(pacc, prs, w2t, c2, out, csl2);
}

// Round 11
// 75.870 us; speedup vs baseline: 1.7965x; 1.7965x over previous
//
#include <hip/hip_runtime.h>
#include <hip/hip_bf16.h>

typedef __attribute__((ext_vector_type(8))) short short8;
typedef __attribute__((ext_vector_type(8))) unsigned short u16x8;
typedef __attribute__((ext_vector_type(4))) unsigned short u16x4;
typedef __attribute__((ext_vector_type(4))) float f32x4;
typedef __attribute__((ext_vector_type(4))) unsigned int u32x4;

#define L2E 1.44269504f

__device__ __forceinline__ unsigned short f2bf(float f){
  unsigned u = __float_as_uint(f);
  u += 0x7fffu + ((u >> 16) & 1u);
  return (unsigned short)(u >> 16);
}
// pack two f32 -> u32 of 2 bf16, RNE, lo in bits[15:0]
__device__ __forceinline__ unsigned pk_bf16(float lo, float hi){
  unsigned a = __float_as_uint(lo);
  a += 0x7fffu + ((a >> 16) & 1u);
  unsigned b = __float_as_uint(hi);
  b += 0x7fffu + ((b >> 16) & 1u);
  return (a >> 16) | (b & 0xffff0000u);
}

// ---------------- prep: fold score_w through q_w / kv_w ----------------
__global__ void prep_vecs(const float* __restrict__ qw, const float* __restrict__ qb,
                          const float* __restrict__ kvw, const float* __restrict__ kvb,
                          const float* __restrict__ scw, const float* __restrict__ scb,
                          float* __restrict__ qv, float* __restrict__ kvv,
                          float* __restrict__ cqck){
  int d = threadIdx.x; // 0..127
  const float4* qr = (const float4*)(qw + d*128);
  const float4* kr = (const float4*)(kvw + d*256);
  float a = 0.f, c = 0.f;
  #pragma unroll 8
  for (int i = 0; i < 32; ++i){
    float4 q4 = qr[i];
    float4 w4 = *(const float4*)(scw + i*4);
    a = fmaf(q4.x, w4.x, a); a = fmaf(q4.y, w4.y, a);
    a = fmaf(q4.z, w4.z, a); a = fmaf(q4.w, w4.w, a);
    float4 k4 = kr[i];
    float4 v4 = *(const float4*)(scw + 128 + i*4);
    c = fmaf(k4.x, v4.x, c); c = fmaf(k4.y, v4.y, c);
    c = fmaf(k4.z, v4.z, c); c = fmaf(k4.w, v4.w, c);
  }
  qv[d] = a; kvv[d] = c;
  if (d == 0){
    float cq = scb[0], ck = 0.f;
    #pragma unroll 8
    for (int i = 0; i < 32; ++i){
      float4 qb4 = *(const float4*)(qb + i*4);
      float4 w4  = *(const float4*)(scw + i*4);
      float4 kb4 = *(const float4*)(kvb + i*4);
      float4 v4  = *(const float4*)(scw + 128 + i*4);
      cq = fmaf(qb4.x, w4.x, cq); cq = fmaf(qb4.y, w4.y, cq);
      cq = fmaf(qb4.z, w4.z, cq); cq = fmaf(qb4.w, w4.w, cq);
      ck = fmaf(kb4.x, v4.x, ck); ck = fmaf(kb4.y, v4.y, ck);
      ck = fmaf(kb4.z, v4.z, ck); ck = fmaf(kb4.w, v4.w, ck);
    }
    cqck[0] = cq; cqck[1] = ck;
  }
}

// W2T[ho][din] = sum_h kv_w[din][128+h] * out_w[h][ho]   (bf16, transposed)
__global__ __launch_bounds__(256) void prep_w2(const float* __restrict__ kvw,
                          const float* __restrict__ kvb,
                          const float* __restrict__ outw, const float* __restrict__ outb,
                          unsigned short* __restrict__ w2t, float* __restrict__ c2){
  int blk = blockIdx.x;
  if (blk < 64){
    int idx = blk*256 + threadIdx.x;
    int di = idx >> 7, ho = idx & 127;
    const float* kr = kvw + di*256 + 128;
    float s = 0.f;
    for (int h = 0; h < 128; ++h) s = fmaf(kr[h], outw[h*128 + ho], s);
    w2t[ho*128 + di] = f2bf(s);
  } else if (threadIdx.x < 128){
    int ho = threadIdx.x;
    float s = outb[ho];
    for (int h = 0; h < 128; ++h) s = fmaf(kvb[128 + h], outw[h*128 + ho], s);
    c2[ho] = s;
  }
}

// sq'[b*1024+m] = L2E * (mf[b,m,:].qv + cq)
__global__ __launch_bounds__(256) void prep_sq(const float* __restrict__ mf,
                          const float* __restrict__ qv, const float* __restrict__ cqck,
                          float* __restrict__ sqp){
  int row = blockIdx.x*4 + (threadIdx.x >> 6);
  int lane = threadIdx.x & 63;
  float s = mf[row*128 + lane] * qv[lane] + mf[row*128 + 64 + lane] * qv[64 + lane];
  #pragma unroll
  for (int o = 32; o; o >>= 1) s += __shfl_xor(s, o, 64);
  if (lane == 0) sqp[row] = L2E * (s + cqck[0]);
}

// sk'[b*4096+c] = L2E*(of[b,c,:].kvv + ck)
// ofTk[b][ksg(128)][l4(4)][d(128)][8] = bf16(of[b][c][d]), c = ksg*32+l4*8+j
__global__ __launch_bounds__(256) void prep_sk_tr(const float* __restrict__ of,
                          const float* __restrict__ kvv, const float* __restrict__ cqck,
                          float* __restrict__ skp, unsigned short* __restrict__ ofTk){
  __shared__ unsigned short tile[64*130];
  int b  = blockIdx.x >> 6;
  int c0 = (blockIdx.x & 63) << 6;
  int t  = threadIdx.x;
  int r  = t >> 2, dq = (t & 3) << 5;
  const float* src = of + ((size_t)(b*4096 + c0 + r))*128 + dq;
  float part = 0.f;
  #pragma unroll
  for (int j = 0; j < 32; j += 4){
    float4 v = *(const float4*)(src + j);
    part = fmaf(v.x, kvv[dq + j],     part);
    part = fmaf(v.y, kvv[dq + j + 1], part);
    part = fmaf(v.z, kvv[dq + j + 2], part);
    part = fmaf(v.w, kvv[dq + j + 3], part);
    tile[r*130 + dq + j]     = f2bf(v.x);
    tile[r*130 + dq + j + 1] = f2bf(v.y);
    tile[r*130 + dq + j + 2] = f2bf(v.z);
    tile[r*130 + dq + j + 3] = f2bf(v.w);
  }
  part += __shfl_xor(part, 1, 64);
  part += __shfl_xor(part, 2, 64);
  if ((t & 3) == 0) skp[b*4096 + c0 + r] = L2E * (part + cqck[1]);
  __syncthreads();
  int d = t >> 1, chh = (t & 1) << 5;
  #pragma unroll
  for (int j = 0; j < 4; ++j){
    int cg = c0 + chh + j*8;
    int ksg = cg >> 5, l4g = (cg >> 3) & 3;
    u16x8 v;
    #pragma unroll
    for (int k = 0; k < 8; ++k) v[k] = tile[(chh + j*8 + k)*130 + d];
    *(u16x8*)(ofTk + (((size_t)(b*128 + ksg)*4 + l4g)*128 + d)*8) = v;
  }
}

// ---------------- main kernel: LDS-free, barrier-free, ordered stream -------
// Wave-private unit = (bmt = b*64+mt16, cs): 16 m-rows x 128 d, c-slice of
// 4096>>CSL2, processed in K-steps of 32 c. Register double/quad buffers:
// B depth 2 (L2), mask depth 4 (HBM), sk depth 2. Issue order == need order
// so in-order vmcnt waits never force-drain young prefetches.
// Rowsum computed by a 9th MFMA against an all-ones B fragment.

#define ISSUE_M(MS, KS) { M##MS##a = *(const float4*)(mbase + (KS)*32);          \
                          M##MS##b = *(const float4*)(mbase + (KS)*32 + 4); }
#define ISSUE_S(SS, KS) { S##SS##a = *(const float4*)(sbase + (KS)*32);          \
                          S##SS##b = *(const float4*)(sbase + (KS)*32 + 4); }
#define ISSUE_B(BS, KS) {                                                        \
  const unsigned short* bp = bbase + (size_t)(KS)*4096;                          \
  B##BS##_0 = *(const short8*)(bp);        B##BS##_1 = *(const short8*)(bp+128); \
  B##BS##_2 = *(const short8*)(bp+256);    B##BS##_3 = *(const short8*)(bp+384); \
  B##BS##_4 = *(const short8*)(bp+512);    B##BS##_5 = *(const short8*)(bp+640); \
  B##BS##_6 = *(const short8*)(bp+768);    B##BS##_7 = *(const short8*)(bp+896); }

#define KSTEP(KS, MS, BS, PFB, PFM)                                              \
{                                                                                \
  float sx[8] = {S##BS##a.x,S##BS##a.y,S##BS##a.z,S##BS##a.w,                    \
                 S##BS##b.x,S##BS##b.y,S##BS##b.z,S##BS##b.w};                   \
  float mx[8] = {M##MS##a.x,M##MS##a.y,M##MS##a.z,M##MS##a.w,                    \
                 M##MS##b.x,M##MS##b.y,M##MS##b.z,M##MS##b.w};                   \
  float pv[8];                                                                   \
  _Pragma("unroll")                                                              \
  for (int j = 0; j < 8; ++j){                                                   \
    float s = sqv + sx[j];            /* log2-domain (pre-scaled by L2E) */      \
    s = fmaxf(s, 0.01f*s);            /* leaky (positively homogeneous) */       \
    s *= mx[j];                       /* mask: 0 -> exp2(0)=1 */                 \
    pv[j] = __builtin_amdgcn_exp2f(s);                                           \
  }                                                                              \
  u32x4 pk;                                                                      \
  pk[0] = pk_bf16(pv[0], pv[1]);                                                 \
  pk[1] = pk_bf16(pv[2], pv[3]);                                                 \
  pk[2] = pk_bf16(pv[4], pv[5]);                                                 \
  pk[3] = pk_bf16(pv[6], pv[7]);                                                 \
  short8 pa = __builtin_bit_cast(short8, pk);                                    \
  accS = __builtin_amdgcn_mfma_f32_16x16x32_bf16(pa, ones, accS, 0, 0, 0);       \
  acc0 = __builtin_amdgcn_mfma_f32_16x16x32_bf16(pa, B##BS##_0, acc0, 0, 0, 0);  \
  acc1 = __builtin_amdgcn_mfma_f32_16x16x32_bf16(pa, B##BS##_1, acc1, 0, 0, 0);  \
  acc2 = __builtin_amdgcn_mfma_f32_16x16x32_bf16(pa, B##BS##_2, acc2, 0, 0, 0);  \
  acc3 = __builtin_amdgcn_mfma_f32_16x16x32_bf16(pa, B##BS##_3, acc3, 0, 0, 0);  \
  acc4 = __builtin_amdgcn_mfma_f32_16x16x32_bf16(pa, B##BS##_4, acc4, 0, 0, 0);  \
  acc5 = __builtin_amdgcn_mfma_f32_16x16x32_bf16(pa, B##BS##_5, acc5, 0, 0, 0);  \
  acc6 = __builtin_amdgcn_mfma_f32_16x16x32_bf16(pa, B##BS##_6, acc6, 0, 0, 0);  \
  acc7 = __builtin_amdgcn_mfma_f32_16x16x32_bf16(pa, B##BS##_7, acc7, 0, 0, 0);  \
  if (PFB){ ISSUE_B(BS, (KS)+2); ISSUE_S(BS, (KS)+2); }                          \
  if (PFM){ ISSUE_M(MS, (KS)+4); }                                              \
}

template<int CSL2>
__global__ __launch_bounds__(256, 2) void attn_main(
    const float* __restrict__ mask, const float* __restrict__ sqp,
    const float* __restrict__ skp, const unsigned short* __restrict__ ofTk,
    float* __restrict__ pacc, float* __restrict__ prs)
{
  constexpr int CS = 1 << CSL2;
  constexpr int NK = 128 >> CSL2;          // K-steps of 32 c
  const int t = threadIdx.x, w = t >> 6, l = t & 63;
  const int l15 = l & 15, l4 = l >> 4;
  const int unit = blockIdx.x*4 + w;
  const int cs   = unit & (CS - 1);
  const int bmt  = unit >> CSL2;           // b*64 + mt16
  const int b    = bmt >> 6;
  const int m0   = (bmt & 63) << 4;
  const int c0   = cs << (12 - CSL2);

  const int grow = b*1024 + m0 + l15;
  const float sqv = sqp[grow];
  const float* mbase = mask + (size_t)grow*4096 + c0 + l4*8;
  const float* sbase = skp + b*4096 + c0 + l4*8;
  const unsigned short* bbase =
      ofTk + (((size_t)(b*128 + (c0 >> 5))*4 + l4)*128 + l15)*8;

  const short one_bf = (short)0x3F80;
  const short8 ones = {one_bf,one_bf,one_bf,one_bf,one_bf,one_bf,one_bf,one_bf};

  f32x4 acc0={0,0,0,0},acc1={0,0,0,0},acc2={0,0,0,0},acc3={0,0,0,0},
        acc4={0,0,0,0},acc5={0,0,0,0},acc6={0,0,0,0},acc7={0,0,0,0},
        accS={0,0,0,0};
  float4 M0a,M0b,M1a,M1b,M2a,M2b,M3a,M3b;
  float4 S0a,S0b,S1a,S1b;
  short8 B0_0,B0_1,B0_2,B0_3,B0_4,B0_5,B0_6,B0_7;
  short8 B1_0,B1_1,B1_2,B1_3,B1_4,B1_5,B1_6,B1_7;

  // prologue: need-order M(0) first
  ISSUE_M(0, 0); ISSUE_S(0, 0);
  ISSUE_B(0, 0);
  ISSUE_M(1, 1); ISSUE_S(1, 1);
  ISSUE_B(1, 1);
  ISSUE_M(2, 2); ISSUE_M(3, 3);

  for (int g = 0; g < NK/4 - 1; ++g){
    const int ks = g*4;
    KSTEP(ks+0, 0, 0, true, true);
    KSTEP(ks+1, 1, 1, true, true);
    KSTEP(ks+2, 2, 0, true, true);
    KSTEP(ks+3, 3, 1, true, true);
  }
  // epilogue: ks = NK-4 .. NK-1 (no M prefetch; B/S only while in range)
  KSTEP(NK-4, 0, 0, true,  false);
  KSTEP(NK-3, 1, 1, true,  false);
  KSTEP(NK-2, 2, 0, false, false);
  KSTEP(NK-1, 3, 1, false, false);

  // rowsum from ones-MFMA: lane (l15, l4) holds rows l4*4+j (cols identical)
  if (l15 == 0) *(f32x4*)(prs + unit*16 + l4*4) = accS;

  // acc -> pacc[unit][col][row] (col = nt*16+l15, rows l4*4..+3)
  float* po = pacc + (size_t)unit*2048 + l15*16 + l4*4;
  *(f32x4*)(po + 0*256) = acc0;  *(f32x4*)(po + 1*256) = acc1;
  *(f32x4*)(po + 2*256) = acc2;  *(f32x4*)(po + 3*256) = acc3;
  *(f32x4*)(po + 4*256) = acc4;  *(f32x4*)(po + 5*256) = acc5;
  *(f32x4*)(po + 6*256) = acc6;  *(f32x4*)(po + 7*256) = acc7;
}

// ---------------- reduce partials + normalize + GEMM2 ----------------
__global__ __launch_bounds__(256) void reduce_gemm2(
    const float* __restrict__ pacc, const float* __restrict__ prs,
    const unsigned short* __restrict__ w2t, const float* __restrict__ c2,
    float* __restrict__ out, int csl2)
{
  __shared__ unsigned short A2[64*128];   // 16 KB, row stride 256 B, swizzled
  __shared__ float rs[64];                // inverse rowsums
  const int bmt64 = blockIdx.x;
  const int b = bmt64 >> 4, mt = bmt64 & 15;
  const int CS = 1 << csl2;
  const int t = threadIdx.x;

  f32x4 a[8];
  #pragma unroll
  for (int i = 0; i < 8; ++i) a[i] = {0.f,0.f,0.f,0.f};
  for (int cs = 0; cs < CS; ++cs){
    #pragma unroll
    for (int i = 0; i < 8; ++i){
      const int flat = (i*256 + t)*4;
      const int q = flat >> 11, f2 = flat & 2047;
      const float* pb = pacc + ((size_t)((bmt64*4 + q)*CS + cs))*2048 + f2;
      f32x4 v = *(const f32x4*)pb;
      a[i][0]+=v[0]; a[i][1]+=v[1]; a[i][2]+=v[2]; a[i][3]+=v[3];
    }
  }
  if (t < 64){
    float s = 0.f;
    const int q = t >> 4, r16 = t & 15;
    for (int cs = 0; cs < CS; ++cs) s += prs[((bmt64*4 + q)*CS + cs)*16 + r16];
    rs[t] = 1.f / s;
  }
  __syncthreads();
  #pragma unroll
  for (int i = 0; i < 8; ++i){
    const int flat = (i*256 + t)*4;
    const int q = flat >> 11, f2 = flat & 2047;
    const int col = f2 >> 4, r16 = f2 & 15;
    #pragma unroll
    for (int k = 0; k < 4; ++k){
      const int row = q*16 + r16 + k;
      unsigned short h = f2bf(a[i][k] * rs[row]);
      *(unsigned short*)((char*)A2 + row*256 + ((col*2) ^ ((row & 7) << 4))) = h;
    }
  }
  __syncthreads();

  const int w = t >> 6, l = t & 63, l15 = l & 15, l4 = l >> 4;
  f32x4 o[4][2];
  #pragma unroll
  for (int mf = 0; mf < 4; ++mf){ o[mf][0] = {0.f,0.f,0.f,0.f}; o[mf][1] = {0.f,0.f,0.f,0.f}; }
  const unsigned short* wp0 = w2t + (size_t)(w*32 + l15)*128 + l4*8;
  const char* ab = (const char*)A2 + l15*256;
  const int xa = (l15 & 7) << 4;
  #pragma unroll
  for (int ks = 0; ks < 4; ++ks){
    short8 b0 = *(const short8*)(wp0 + ks*32);
    short8 b1 = *(const short8*)(wp0 + 16*128 + ks*32);
    #pragma unroll
    for (int mf = 0; mf < 4; ++mf){
      short8 af = *(const short8*)(ab + mf*4096 + ((ks*64 + l4*16) ^ xa));
      o[mf][0] = __builtin_amdgcn_mfma_f32_16x16x32_bf16(af, b0, o[mf][0], 0, 0, 0);
      o[mf][1] = __builtin_amdgcn_mfma_f32_16x16x32_bf16(af, b1, o[mf][1], 0, 0, 0);
    }
  }
  #pragma unroll
  for (int mf = 0; mf < 4; ++mf)
    #pragma unroll
    for (int n = 0; n < 2; ++n){
      const int col = w*32 + n*16 + l15;
      const float cc = c2[col];
      #pragma unroll
      for (int j = 0; j < 4; ++j){
        const int row = mf*16 + l4*4 + j;
        out[((size_t)(b*1024 + mt*64 + row))*128 + col] = o[mf][n][j] + cc;
      }
    }
}

extern "C" void kernel_launch(void* const* d_in, const int* in_sizes, int n_in,
                              void* d_out, int out_size, void* d_ws, size_t ws_size,
                              hipStream_t stream){
  const float* of   = (const float*)d_in[0];
  const float* mf   = (const float*)d_in[1];
  const float* mask = (const float*)d_in[2];
  const float* qw   = (const float*)d_in[3];
  const float* qb   = (const float*)d_in[4];
  const float* kvw  = (const float*)d_in[5];
  const float* kvb  = (const float*)d_in[6];
  const float* scw  = (const float*)d_in[7];
  const float* scb  = (const float*)d_in[8];
  const float* outw = (const float*)d_in[9];
  const float* outb = (const float*)d_in[10];
  float* out = (float*)d_out;

  char* ws = (char*)d_ws;
  unsigned short* ofTk = (unsigned short*)(ws);             // 8 MiB
  unsigned short* w2t  = (unsigned short*)(ws + 8388608);   // 32 KiB
  float* c2   = (float*)(ws + 8421376);
  float* sqp  = (float*)(ws + 8421888);
  float* skp  = (float*)(ws + 8454656);
  float* qv   = (float*)(ws + 8585728);
  float* kvv  = (float*)(ws + 8586240);
  float* cqck = (float*)(ws + 8586752);
  const size_t fixed_end = 8587008;

  // units = 512 << csl2 (one wave each)
  int csl2 = 2;
  while (csl2 > 1){
    size_t nunit = (size_t)512 << csl2;
    if (fixed_end + nunit*16*4 + nunit*2048*4 <= ws_size) break;
    --csl2;
  }
  size_t nunit = (size_t)512 << csl2;
  float* prs  = (float*)(ws + fixed_end);
  float* pacc = (float*)(ws + fixed_end + nunit*16*4);
  int nblk = (int)(nunit >> 2);

  prep_vecs<<<1, 128, 0, stream>>>(qw, qb, kvw, kvb, scw, scb, qv, kvv, cqck);
  prep_w2<<<65, 256, 0, stream>>>(kvw, kvb, outw, outb, w2t, c2);
  prep_sq<<<2048, 256, 0, stream>>>(mf, qv, cqck, sqp);
  prep_sk_tr<<<512, 256, 0, stream>>>(of, kvv, cqck, skp, ofTk);
  if (csl2 == 2)
    attn_main<2><<<nblk, 256, 0, stream>>>(mask, sqp, skp, ofTk, pacc, prs);
  else
    attn_main<1><<<nblk, 256, 0, stream>>>(mask, sqp, skp, ofTk, pacc, prs);
  reduce_gemm2<<<128, 256, 0, stream>>>(pacc, prs, w2t, c2, out, csl2);
}